// Round 1
// baseline (18741.516 us; speedup 1.0000x reference)
//
#include <hip/hip_runtime.h>
#include <hip/hip_bf16.h>
#include <cstdint>

#define B_ 2
#define S_ 2048
#define H_ 2048
#define NH_ 16
#define QL_ 1536
#define KVL_ 512
#define NOPE_ 128
#define ROPE_ 64
#define QHD_ 192
#define VHD_ 128
#define FF_ 8192
#define BS_ (B_ * S_)            // 4096 rows
#define CKVW_ (KVL_ + ROPE_)     // 576
#define KVW_ (NOPE_ + VHD_)      // 256 per head

// ---------------------------------------------------------------------------
// RMSNorm: one block (256 threads) per row. float4 loads. Optional strides
// so we can normalize a column-slice of ckv into a compact buffer.
// ---------------------------------------------------------------------------
__global__ __launch_bounds__(256) void rmsnorm_kernel(
    const float* __restrict__ in, const float* __restrict__ w,
    float* __restrict__ out, int cols, int in_stride, int out_stride)
{
    const int row = blockIdx.x;
    const float* ip = in + (size_t)row * in_stride;
    float* op = out + (size_t)row * out_stride;
    const int c4 = cols >> 2;
    const float4* ip4 = (const float4*)ip;
    const float4* w4  = (const float4*)w;
    float4* op4 = (float4*)op;

    float ss = 0.f;
    for (int c = threadIdx.x; c < c4; c += 256) {
        float4 v = ip4[c];
        ss = fmaf(v.x, v.x, fmaf(v.y, v.y, fmaf(v.z, v.z, fmaf(v.w, v.w, ss))));
    }
    #pragma unroll
    for (int off = 32; off; off >>= 1) ss += __shfl_xor(ss, off);
    __shared__ float red[4];
    if ((threadIdx.x & 63) == 0) red[threadIdx.x >> 6] = ss;
    __syncthreads();
    const float total = red[0] + red[1] + red[2] + red[3];
    const float scale = rsqrtf(total / (float)cols + 1e-6f);
    for (int c = threadIdx.x; c < c4; c += 256) {
        float4 v = ip4[c];
        float4 g = w4[c];
        float4 o;
        o.x = v.x * scale * g.x;
        o.y = v.y * scale * g.y;
        o.z = v.z * scale * g.z;
        o.w = v.w * scale * g.w;
        op4[c] = o;
    }
}

// ---------------------------------------------------------------------------
// SGEMM: C(MxN) = A(MxK) @ B(KxN), row-major. 128x128 tile, BK=16,
// 256 threads each computing 8x8. Epilogue modes:
//   0: C = acc
//   1: C = acc + D          (residual add; D may alias C)
//   2: C = silu(D) * acc    (fused gate*up; D may alias C)
// ---------------------------------------------------------------------------
#define BM 128
#define BN 128
#define BK 16

__global__ __launch_bounds__(256) void sgemm_kernel(
    const float* __restrict__ A, const float* __restrict__ Bm,
    const float* __restrict__ D, float* __restrict__ C,
    int M, int N, int K, int mode)
{
    __shared__ __align__(16) float As[BK][BM + 4];
    __shared__ __align__(16) float Bs[BK][BN + 4];

    const int tid = threadIdx.x;
    const int tx = tid & 15;   // 0..15 -> column group of 8
    const int ty = tid >> 4;   // 0..15 -> row group of 8
    const int bm = blockIdx.y * BM;
    const int bn = blockIdx.x * BN;

    float acc[8][8] = {};

    for (int k0 = 0; k0 < K; k0 += BK) {
        #pragma unroll
        for (int r = 0; r < 8; ++r) {
            int idx = tid + r * 256;          // 0..2047
            int m = idx >> 4, kk = idx & 15;
            int gm = bm + m;
            As[kk][m] = (gm < M) ? A[(size_t)gm * K + k0 + kk] : 0.f;
        }
        #pragma unroll
        for (int r = 0; r < 8; ++r) {
            int idx = tid + r * 256;
            int kk = idx >> 7, n = idx & 127;
            int gn = bn + n;
            Bs[kk][n] = (gn < N) ? Bm[(size_t)(k0 + kk) * N + gn] : 0.f;
        }
        __syncthreads();
        #pragma unroll
        for (int kk = 0; kk < BK; ++kk) {
            float a[8], b[8];
            *(float4*)&a[0] = *(const float4*)&As[kk][ty * 8];
            *(float4*)&a[4] = *(const float4*)&As[kk][ty * 8 + 4];
            *(float4*)&b[0] = *(const float4*)&Bs[kk][tx * 8];
            *(float4*)&b[4] = *(const float4*)&Bs[kk][tx * 8 + 4];
            #pragma unroll
            for (int i = 0; i < 8; ++i)
                #pragma unroll
                for (int j = 0; j < 8; ++j)
                    acc[i][j] = fmaf(a[i], b[j], acc[i][j]);
        }
        __syncthreads();
    }

    #pragma unroll
    for (int i = 0; i < 8; ++i) {
        const int gm = bm + ty * 8 + i;
        if (gm >= M) continue;
        #pragma unroll
        for (int j = 0; j < 8; ++j) {
            const int gn = bn + tx * 8 + j;
            if (gn >= N) continue;
            const size_t off = (size_t)gm * N + gn;
            float v = acc[i][j];
            if (mode == 1) {
                v += D[off];
            } else if (mode == 2) {
                const float g = D[off];
                v *= g / (1.f + __expf(-g));
            }
            C[off] = v;
        }
    }
}

// ---------------------------------------------------------------------------
// RoPE (deinterleave + rotate). One wave per 64-dim slice.
// Slices: B*S*NH q_pe slices (q[...,128:192]) then B*S k_pe slices
// (ckv[...,512:576]). Done in-register via shuffles -> no read/write race.
//   y[j] = x[2j], y[j+32] = x[2j+1]
//   out[l<32]  = x[2l]*cos[l]   - x[2l+1]*sin[l]
//   out[l>=32] = x[2j+1]*cos[l] + x[2j]*sin[l]   (j = l-32; cos[l]==cos[j])
// ---------------------------------------------------------------------------
__global__ __launch_bounds__(256) void rope_kernel(
    float* __restrict__ q, float* __restrict__ ckv,
    const int* __restrict__ pos_ids,
    const float* __restrict__ sinT, const float* __restrict__ cosT)
{
    const int wid = blockIdx.x * 4 + (threadIdx.x >> 6);
    const int lane = threadIdx.x & 63;
    const int NQ = BS_ * NH_;

    float* ptr;
    int bs;
    if (wid < NQ) {
        bs = wid >> 4;  // wid = bs*NH + h
        ptr = q + (size_t)wid * QHD_ + NOPE_;
    } else if (wid < NQ + BS_) {
        bs = wid - NQ;
        ptr = ckv + (size_t)bs * CKVW_ + KVL_;
    } else {
        return;
    }
    const int pos = pos_ids[bs];
    const float c  = cosT[pos * ROPE_ + lane];
    const float sn = sinT[pos * ROPE_ + lane];
    const float x = ptr[lane];
    const int j = lane & 31;
    const float x0 = __shfl(x, 2 * j);
    const float x1 = __shfl(x, 2 * j + 1);
    ptr[lane] = (lane < 32) ? fmaf(x0, c, -x1 * sn) : fmaf(x1, c, x0 * sn);
}

// ---------------------------------------------------------------------------
// Flash-style causal attention. One wave (64 threads) per (b, h, q-row).
// Per 64-k block: lane l computes full dot for k=k0+l (q broadcast from LDS),
// wave-level online softmax, then PV via shuffle-broadcast of p.
// q:   (B,S,NH,192)   [0:128] nope, [128:192] rope'd pe
// kv:  (B,S,NH,256)   [0:128] k_nope, [128:256] v
// ckv: (B,S,576)      [512:576] rope'd k_pe (shared across heads)
// out: (B,S,NH,128)
// ---------------------------------------------------------------------------
__global__ __launch_bounds__(64) void attn_kernel(
    const float* __restrict__ q, const float* __restrict__ kv,
    const float* __restrict__ ckv, float* __restrict__ out)
{
    const int qi = blockIdx.x;
    const int h  = blockIdx.y;
    const int b  = blockIdx.z;
    const int lane = threadIdx.x;

    __shared__ __align__(16) float qs[QHD_];
    const float* qrow = q + (((size_t)b * S_ + qi) * NH_ + h) * QHD_;
    if (lane < 48) ((float4*)qs)[lane] = ((const float4*)qrow)[lane];
    __syncthreads();

    const float scale = 0.07216878364870323f;  // 192^-0.5
    const float4* q4 = (const float4*)qs;

    float m = -INFINITY, lsum = 0.f, acc0 = 0.f, acc1 = 0.f;

    for (int k0 = 0; k0 <= qi; k0 += 64) {
        const int k = k0 + lane;
        float s = -INFINITY;
        if (k <= qi) {
            const float4* k4  = (const float4*)(kv + (((size_t)b * S_ + k) * NH_ + h) * KVW_);
            const float4* kp4 = (const float4*)(ckv + ((size_t)b * S_ + k) * CKVW_ + KVL_);
            float d0 = 0.f;
            #pragma unroll
            for (int d = 0; d < 32; ++d) {
                float4 kk = k4[d], qq = q4[d];
                d0 = fmaf(kk.x, qq.x, fmaf(kk.y, qq.y, fmaf(kk.z, qq.z, fmaf(kk.w, qq.w, d0))));
            }
            #pragma unroll
            for (int d = 0; d < 16; ++d) {
                float4 kk = kp4[d], qq = q4[32 + d];
                d0 = fmaf(kk.x, qq.x, fmaf(kk.y, qq.y, fmaf(kk.z, qq.z, fmaf(kk.w, qq.w, d0))));
            }
            s = d0 * scale;
        }
        // wave max
        float bmx = s;
        #pragma unroll
        for (int off = 32; off; off >>= 1) bmx = fmaxf(bmx, __shfl_xor(bmx, off));
        const float mnew = fmaxf(m, bmx);
        const float corr = __expf(m - mnew);  // exp(-inf)=0 on first block
        const float p = (k <= qi) ? __expf(s - mnew) : 0.f;
        float psum = p;
        #pragma unroll
        for (int off = 32; off; off >>= 1) psum += __shfl_xor(psum, off);
        lsum = lsum * corr + psum;
        acc0 *= corr;
        acc1 *= corr;
        m = mnew;
        // PV: p==0 for k>qi, and k0+63 < S always, so run all 64 lanes.
        const float* vbase = kv + (((size_t)b * S_ + k0) * NH_ + h) * KVW_ + NOPE_;
        #pragma unroll 16
        for (int j = 0; j < 64; ++j) {
            const float pj = __shfl(p, j);
            const float* vrow = vbase + (size_t)j * (NH_ * KVW_);
            acc0 = fmaf(pj, vrow[lane], acc0);
            acc1 = fmaf(pj, vrow[lane + 64], acc1);
        }
    }
    const float inv = 1.f / lsum;
    float* orow = out + (((size_t)b * S_ + qi) * NH_ + h) * VHD_;
    orow[lane] = acc0 * inv;
    orow[lane + 64] = acc1 * inv;
}

// ---------------------------------------------------------------------------
// Launch
// ---------------------------------------------------------------------------
extern "C" void kernel_launch(void* const* d_in, const int* in_sizes, int n_in,
                              void* d_out, int out_size, void* d_ws, size_t ws_size,
                              hipStream_t stream)
{
    const float* hidden  = (const float*)d_in[0];
    const float* ln1_w   = (const float*)d_in[1];
    const float* q_a_k   = (const float*)d_in[2];
    const float* q_a_ln  = (const float*)d_in[3];
    const float* q_b_k   = (const float*)d_in[4];
    const float* kv_a_k  = (const float*)d_in[5];
    const float* kv_a_ln = (const float*)d_in[6];
    const float* kv_b_k  = (const float*)d_in[7];
    const float* o_k     = (const float*)d_in[8];
    const float* ln2_w   = (const float*)d_in[9];
    const float* gate_k  = (const float*)d_in[10];
    const float* up_k    = (const float*)d_in[11];
    const float* down_k  = (const float*)d_in[12];
    const float* sinT    = (const float*)d_in[13];
    const float* cosT    = (const float*)d_in[14];
    const int*   pos     = (const int*)d_in[15];
    float* out = (float*)d_out;
    float* ws  = (float*)d_ws;

    // Workspace layout (floats). ATTN aliases dead QA+CKVN; MLP aliases dead Q+KV.
    float* X    = ws;                                  // BS*H      = 8,388,608
    float* CKV  = X    + (size_t)BS_ * H_;             // BS*576    = 2,359,296
    float* QA   = CKV  + (size_t)BS_ * CKVW_;          // BS*1536   = 6,291,456
    float* CKVN = QA   + (size_t)BS_ * QL_;            // BS*512    = 2,097,152
    float* Qb   = CKVN + (size_t)BS_ * KVL_;           // BS*3072   = 12,582,912
    float* KV   = Qb   + (size_t)BS_ * (NH_ * QHD_);   // BS*4096   = 16,777,216
    float* ATTN = QA;                                  // BS*2048 (QA+CKVN region)
    float* MLP  = Qb;                                  // BS*8192 (Qb+KV region)

    // 1. x = rmsnorm(hidden, ln1_w)
    rmsnorm_kernel<<<BS_, 256, 0, stream>>>(hidden, ln1_w, X, H_, H_, H_);
    // 2. QA = x @ q_a_kernel
    sgemm_kernel<<<dim3(QL_ / BN, BS_ / BM), 256, 0, stream>>>(X, q_a_k, nullptr, QA, BS_, QL_, H_, 0);
    // 3. QA = rmsnorm(QA, q_a_ln_w) (in place)
    rmsnorm_kernel<<<BS_, 256, 0, stream>>>(QA, q_a_ln, QA, QL_, QL_, QL_);
    // 4. Q = QA @ q_b_kernel   (B,S,NH*192)
    sgemm_kernel<<<dim3((NH_ * QHD_) / BN, BS_ / BM), 256, 0, stream>>>(QA, q_b_k, nullptr, Qb, BS_, NH_ * QHD_, QL_, 0);
    // 5. CKV = x @ kv_a_kernel  (B,S,576)
    sgemm_kernel<<<dim3((CKVW_ + BN - 1) / BN, BS_ / BM), 256, 0, stream>>>(X, kv_a_k, nullptr, CKV, BS_, CKVW_, H_, 0);
    // 6. CKVN = rmsnorm(CKV[:, :512], kv_a_ln_w)
    rmsnorm_kernel<<<BS_, 256, 0, stream>>>(CKV, kv_a_ln, CKVN, KVL_, CKVW_, KVL_);
    // 7. KV = CKVN @ kv_b_kernel  (B,S,NH*256)
    sgemm_kernel<<<dim3((NH_ * KVW_) / BN, BS_ / BM), 256, 0, stream>>>(CKVN, kv_b_k, nullptr, KV, BS_, NH_ * KVW_, KVL_, 0);
    // 8. RoPE on q_pe (in Qb) and k_pe (in CKV), in place
    {
        const int waves = BS_ * NH_ + BS_;  // 69632
        rope_kernel<<<waves / 4, 256, 0, stream>>>(Qb, CKV, pos, sinT, cosT);
    }
    // 9. attention -> ATTN (B,S,NH,128)
    attn_kernel<<<dim3(S_, NH_, B_), 64, 0, stream>>>(Qb, KV, CKV, ATTN);
    // 10. h1 = ATTN @ o_kernel + hidden -> d_out
    sgemm_kernel<<<dim3(H_ / BN, BS_ / BM), 256, 0, stream>>>(ATTN, o_k, hidden, out, BS_, H_, NH_ * VHD_, 1);
    // 11. x2 = rmsnorm(h1, ln2_w) -> X
    rmsnorm_kernel<<<BS_, 256, 0, stream>>>(out, ln2_w, X, H_, H_, H_);
    // 12. MLP = x2 @ gate_kernel
    sgemm_kernel<<<dim3(FF_ / BN, BS_ / BM), 256, 0, stream>>>(X, gate_k, nullptr, MLP, BS_, FF_, H_, 0);
    // 13. MLP = silu(MLP) * (x2 @ up_kernel)
    sgemm_kernel<<<dim3(FF_ / BN, BS_ / BM), 256, 0, stream>>>(X, up_k, MLP, MLP, BS_, FF_, H_, 2);
    // 14. d_out = h1 + MLP @ down_kernel
    sgemm_kernel<<<dim3(H_ / BN, BS_ / BM), 256, 0, stream>>>(MLP, down_k, out, out, BS_, H_, FF_, 1);
}

// Round 2
// 8084.677 us; speedup vs baseline: 2.3182x; 2.3182x over previous
//
#include <hip/hip_runtime.h>
#include <hip/hip_bf16.h>
#include <cstdint>

#define B_ 2
#define S_ 2048
#define H_ 2048
#define NH_ 16
#define QL_ 1536
#define KVL_ 512
#define NOPE_ 128
#define ROPE_ 64
#define QHD_ 192
#define VHD_ 128
#define FF_ 8192
#define BS_ (B_ * S_)            // 4096 rows
#define CKVP_ 640                // padded ckv width (576 -> 640 for N%128==0)
#define KVW_ (NOPE_ + VHD_)      // 256 per head

typedef __hip_bfloat16 bf16;
typedef __attribute__((ext_vector_type(8))) short short8_t;  // 8 bf16 (4 VGPRs)
typedef __attribute__((ext_vector_type(4))) float f32x4;

__device__ __forceinline__ float ldf(const float* p, size_t i) { return p[i]; }
__device__ __forceinline__ float ldf(const bf16* p, size_t i) { return __bfloat162float(p[i]); }
__device__ __forceinline__ void stf(float* p, size_t i, float v) { p[i] = v; }
__device__ __forceinline__ void stf(bf16* p, size_t i, float v) { p[i] = __float2bfloat16(v); }

// ---------------------------------------------------------------------------
// Transpose + convert: in fp32 [K][N] -> out bf16 [Npad][K]; rows n>=N zeroed.
// ---------------------------------------------------------------------------
__global__ __launch_bounds__(256) void transp_bf16(
    const float* __restrict__ in, bf16* __restrict__ out, int K, int N, int Npad)
{
    __shared__ float t[32][33];
    const int n0 = blockIdx.x * 32, k0 = blockIdx.y * 32;
    for (int r = threadIdx.y; r < 32; r += 8) {
        const int n = n0 + threadIdx.x;
        t[r][threadIdx.x] = (n < N) ? in[(size_t)(k0 + r) * N + n] : 0.f;
    }
    __syncthreads();
    for (int r = threadIdx.y; r < 32; r += 8) {
        out[(size_t)(n0 + r) * K + k0 + threadIdx.x] = __float2bfloat16(t[threadIdx.x][r]);
    }
}

// ---------------------------------------------------------------------------
// RMSNorm (templated dtypes): one 256-thread block per row.
// ---------------------------------------------------------------------------
template<typename InT, typename OutT>
__global__ __launch_bounds__(256) void rmsnorm2(
    const InT* __restrict__ in, const float* __restrict__ w,
    OutT* __restrict__ out, int cols, int istride, int ostride)
{
    const int row = blockIdx.x;
    const InT* ip = in + (size_t)row * istride;
    OutT* op = out + (size_t)row * ostride;

    float ss = 0.f;
    for (int c = threadIdx.x; c < cols; c += 256) {
        float v = ldf(ip, c);
        ss = fmaf(v, v, ss);
    }
    #pragma unroll
    for (int off = 32; off; off >>= 1) ss += __shfl_xor(ss, off);
    __shared__ float red[4];
    if ((threadIdx.x & 63) == 0) red[threadIdx.x >> 6] = ss;
    __syncthreads();
    const float total = red[0] + red[1] + red[2] + red[3];
    const float scale = rsqrtf(total / (float)cols + 1e-6f);
    for (int c = threadIdx.x; c < cols; c += 256) {
        stf(op, c, ldf(ip, c) * scale * w[c]);
    }
}

// ---------------------------------------------------------------------------
// bf16 MFMA GEMM (m97 structure): C[M][N] = A[M][K] @ BT[N][K]^T
// 128x128 tile, BK=32, 4 waves (2x2), each wave 4x4 frags of 16x16x32.
// MODE 0: C = acc; 1: C = acc + Df; 2: C = silu(Db)*acc.
// Requires M%128==0, N%128==0, K%32==0.
// ---------------------------------------------------------------------------
__device__ __forceinline__ void gload16(const void* g, void* l)
{
    __builtin_amdgcn_global_load_lds((const unsigned int*)g, (unsigned int*)l, 16, 0, 0);
}

template<int MODE, typename OutT>
__global__ __launch_bounds__(256) void gemm_bf16(
    const bf16* __restrict__ A, const bf16* __restrict__ BT,
    const float* __restrict__ Df, const bf16* __restrict__ Db,
    OutT* __restrict__ C, int M, int N, int K)
{
    __shared__ short As[128 * 32];
    __shared__ short Bs[128 * 32];
    const int tid = threadIdx.x;
    const int wid = tid >> 6, lane = tid & 63;
    const int bm = blockIdx.y * 128, bn = blockIdx.x * 128;
    const int wr = (wid >> 1) * 64, wc = (wid & 1) * 64;
    const int l16 = lane & 15;
    const int lk = (lane >> 4) << 3;

    f32x4 acc[4][4] = {};

    for (int k0 = 0; k0 < K; k0 += 32) {
        // stage A,B tiles: 512 chunks of 16B each, 2 issues x 256 threads
        #pragma unroll
        for (int is = 0; is < 2; ++is) {
            const int c = is * 256 + tid;             // chunk id (per-lane)
            const int row = c >> 2;
            const int cb = (c & 3) * 16;              // byte offset within row
            const char* srcA = (const char*)A + ((size_t)(bm + row) * K + k0) * 2 + cb;
            const char* srcB = (const char*)BT + ((size_t)(bn + row) * K + k0) * 2 + cb;
            char* dstA = (char*)As + (is * 256 + wid * 64) * 16;   // wave-uniform base
            char* dstB = (char*)Bs + (is * 256 + wid * 64) * 16;
            gload16(srcA, dstA);
            gload16(srcB, dstB);
        }
        __syncthreads();

        short8_t a[4], b[4];
        const short* ApW = As + (wr + l16) * 32 + lk;
        const short* BpW = Bs + (wc + l16) * 32 + lk;
        #pragma unroll
        for (int m = 0; m < 4; ++m) a[m] = *(const short8_t*)(ApW + m * 16 * 32);
        #pragma unroll
        for (int n = 0; n < 4; ++n) b[n] = *(const short8_t*)(BpW + n * 16 * 32);
        #pragma unroll
        for (int m = 0; m < 4; ++m)
            #pragma unroll
            for (int n = 0; n < 4; ++n)
                acc[m][n] = __builtin_amdgcn_mfma_f32_16x16x32_bf16(a[m], b[n], acc[m][n], 0, 0, 0);
        __syncthreads();
    }

    const int r0 = bm + wr + ((lane >> 4) << 2);
    const int c0 = bn + wc + l16;
    #pragma unroll
    for (int m = 0; m < 4; ++m) {
        #pragma unroll
        for (int n = 0; n < 4; ++n) {
            const int row = r0 + m * 16;
            const int col = c0 + n * 16;
            #pragma unroll
            for (int r = 0; r < 4; ++r) {
                const size_t off = (size_t)(row + r) * N + col;
                float v = acc[m][n][r];
                if (MODE == 1) v += Df[off];
                if (MODE == 2) {
                    const float g = __bfloat162float(Db[off]);
                    v *= g / (1.f + __expf(-g));
                }
                stf(C, off, v);
            }
        }
    }
}

// ---------------------------------------------------------------------------
// RoPE: one wave per 64-dim slice. q is bf16 (B,S,NH,192), k_pe fp32 in
// ckv (B,S,640)[512:576]. In-register deinterleave+rotate via shuffles.
// ---------------------------------------------------------------------------
__global__ __launch_bounds__(256) void rope_kernel(
    bf16* __restrict__ q, float* __restrict__ ckv,
    const int* __restrict__ pos_ids,
    const float* __restrict__ sinT, const float* __restrict__ cosT)
{
    const int wid = blockIdx.x * 4 + (threadIdx.x >> 6);
    const int lane = threadIdx.x & 63;
    const int NQ = BS_ * NH_;

    int bs;
    bf16* bptr = nullptr;
    float* fptr = nullptr;
    if (wid < NQ) {
        bs = wid >> 4;
        bptr = q + (size_t)wid * QHD_ + NOPE_;
    } else {
        bs = wid - NQ;
        fptr = ckv + (size_t)bs * CKVP_ + KVL_;
    }
    const int pos = pos_ids[bs];
    const float c  = cosT[pos * ROPE_ + lane];
    const float sn = sinT[pos * ROPE_ + lane];
    const float x = bptr ? __bfloat162float(bptr[lane]) : fptr[lane];
    const int j = lane & 31;
    const float x0 = __shfl(x, 2 * j);
    const float x1 = __shfl(x, 2 * j + 1);
    const float res = (lane < 32) ? fmaf(x0, c, -x1 * sn) : fmaf(x1, c, x0 * sn);
    if (bptr) bptr[lane] = __float2bfloat16(res);
    else      fptr[lane] = res;
}

// ---------------------------------------------------------------------------
// Flash-style causal attention, 4 waves/block, each wave owns one q-row.
// q bf16 (B,S,NH,192); kv fp32 (B,S,NH,256) [0:128] k_nope [128:256] v;
// ckv fp32 (B,S,640) [512:576] rope'd k_pe; out bf16 (B,S,NH,128).
// ---------------------------------------------------------------------------
__global__ __launch_bounds__(256) void attn_kernel(
    const bf16* __restrict__ q, const float* __restrict__ kv,
    const float* __restrict__ ckv, bf16* __restrict__ out)
{
    const int w = threadIdx.x >> 6;
    const int lane = threadIdx.x & 63;
    const int qi = blockIdx.x * 4 + w;
    const int h  = blockIdx.y;
    const int b  = blockIdx.z;

    __shared__ __align__(16) float qs[4][QHD_];
    const bf16* qrow = q + (((size_t)b * S_ + qi) * NH_ + h) * QHD_;
    if (lane < 48) {
        #pragma unroll
        for (int i = 0; i < 4; ++i)
            qs[w][lane * 4 + i] = __bfloat162float(qrow[lane * 4 + i]);
    }
    __syncthreads();

    const float scale = 0.07216878364870323f;  // 192^-0.5
    const float4* q4 = (const float4*)qs[w];

    float m = -INFINITY, lsum = 0.f, acc0 = 0.f, acc1 = 0.f;

    for (int k0 = 0; k0 <= qi; k0 += 64) {
        const int k = k0 + lane;
        float s = -INFINITY;
        if (k <= qi) {
            const float4* k4  = (const float4*)(kv + (((size_t)b * S_ + k) * NH_ + h) * KVW_);
            const float4* kp4 = (const float4*)(ckv + ((size_t)b * S_ + k) * CKVP_ + KVL_);
            float d0 = 0.f;
            #pragma unroll
            for (int d = 0; d < 32; ++d) {
                float4 kk = k4[d], qq = q4[d];
                d0 = fmaf(kk.x, qq.x, fmaf(kk.y, qq.y, fmaf(kk.z, qq.z, fmaf(kk.w, qq.w, d0))));
            }
            #pragma unroll
            for (int d = 0; d < 16; ++d) {
                float4 kk = kp4[d], qq = q4[32 + d];
                d0 = fmaf(kk.x, qq.x, fmaf(kk.y, qq.y, fmaf(kk.z, qq.z, fmaf(kk.w, qq.w, d0))));
            }
            s = d0 * scale;
        }
        float bmx = s;
        #pragma unroll
        for (int off = 32; off; off >>= 1) bmx = fmaxf(bmx, __shfl_xor(bmx, off));
        const float mnew = fmaxf(m, bmx);
        const float corr = __expf(m - mnew);
        const float p = (k <= qi) ? __expf(s - mnew) : 0.f;
        float psum = p;
        #pragma unroll
        for (int off = 32; off; off >>= 1) psum += __shfl_xor(psum, off);
        lsum = lsum * corr + psum;
        acc0 *= corr;
        acc1 *= corr;
        m = mnew;
        const float* vbase = kv + (((size_t)b * S_ + k0) * NH_ + h) * KVW_ + NOPE_;
        #pragma unroll 16
        for (int j = 0; j < 64; ++j) {
            const float pj = __shfl(p, j);
            const float* vrow = vbase + (size_t)j * (NH_ * KVW_);
            acc0 = fmaf(pj, vrow[lane], acc0);
            acc1 = fmaf(pj, vrow[lane + 64], acc1);
        }
    }
    const float inv = 1.f / lsum;
    bf16* orow = out + (((size_t)b * S_ + qi) * NH_ + h) * VHD_;
    orow[lane] = __float2bfloat16(acc0 * inv);
    orow[lane + 64] = __float2bfloat16(acc1 * inv);
}

// ---------------------------------------------------------------------------
// Launch
// ---------------------------------------------------------------------------
extern "C" void kernel_launch(void* const* d_in, const int* in_sizes, int n_in,
                              void* d_out, int out_size, void* d_ws, size_t ws_size,
                              hipStream_t stream)
{
    const float* hidden  = (const float*)d_in[0];
    const float* ln1_w   = (const float*)d_in[1];
    const float* q_a_k   = (const float*)d_in[2];
    const float* q_a_ln  = (const float*)d_in[3];
    const float* q_b_k   = (const float*)d_in[4];
    const float* kv_a_k  = (const float*)d_in[5];
    const float* kv_a_ln = (const float*)d_in[6];
    const float* kv_b_k  = (const float*)d_in[7];
    const float* o_k     = (const float*)d_in[8];
    const float* ln2_w   = (const float*)d_in[9];
    const float* gate_k  = (const float*)d_in[10];
    const float* up_k    = (const float*)d_in[11];
    const float* down_k  = (const float*)d_in[12];
    const float* sinT    = (const float*)d_in[13];
    const float* cosT    = (const float*)d_in[14];
    const int*   pos     = (const int*)d_in[15];
    float* out = (float*)d_out;
    char* ws = (char*)d_ws;

    // ---- Phase-1 workspace layout (bytes) — peak 184.0 MB ----
    bf16* qaT   = (bf16*)(ws + 0);            // [1536][2048]  6,291,456
    bf16* qbT   = (bf16*)(ws + 6291456);      // [3072][1536]  9,437,184
    bf16* kvaT  = (bf16*)(ws + 15728640);     // [640][2048]   2,621,440 (zero-padded rows 576..639)
    bf16* kvbT  = (bf16*)(ws + 18350080);     // [4096][512]   4,194,304
    bf16* oT    = (bf16*)(ws + 22544384);     // [2048][2048]  8,388,608
    bf16* Xb    = (bf16*)(ws + 30932992);     // [4096][2048] 16,777,216
    bf16* QAb   = (bf16*)(ws + 47710208);     // [4096][1536] 12,582,912
    bf16* CKVNb = (bf16*)(ws + 60293120);     // [4096][512]   4,194,304
    bf16* Qb    = (bf16*)(ws + 64487424);     // [4096][3072] 25,165,824
    float* CKV  = (float*)(ws + 89653248);    // [4096][640]  10,485,760
    float* KV   = (float*)(ws + 100139008);   // [4096][4096] 67,108,864
    bf16* ATTNb = (bf16*)(ws + 167247872);    // [4096][2048] 16,777,216 (ends 184,025,088)
    // ---- Phase-2 layout (reuses everything; after o-GEMM) — peak 184.5 MB ----
    bf16* gateT = (bf16*)(ws + 0);            // [8192][2048] 33,554,432
    bf16* upT   = (bf16*)(ws + 33554432);     // [8192][2048] 33,554,432
    bf16* downT = (bf16*)(ws + 67108864);     // [2048][8192] 33,554,432
    bf16* X2b   = (bf16*)(ws + 100663296);    // [4096][2048] 16,777,216
    bf16* MLPb  = (bf16*)(ws + 117440512);    // [4096][8192] 67,108,864 (ends 184,549,376)

    const dim3 tb(32, 8);

    // 0. weight transposes (attention-phase weights)
    transp_bf16<<<dim3(1536 / 32, 2048 / 32), tb, 0, stream>>>(q_a_k, qaT, 2048, 1536, 1536);
    transp_bf16<<<dim3(3072 / 32, 1536 / 32), tb, 0, stream>>>(q_b_k, qbT, 1536, 3072, 3072);
    transp_bf16<<<dim3(640 / 32, 2048 / 32), tb, 0, stream>>>(kv_a_k, kvaT, 2048, 576, 640);
    transp_bf16<<<dim3(4096 / 32, 512 / 32), tb, 0, stream>>>(kv_b_k, kvbT, 512, 4096, 4096);
    transp_bf16<<<dim3(2048 / 32, 2048 / 32), tb, 0, stream>>>(o_k, oT, 2048, 2048, 2048);

    // 1. Xb = rmsnorm(hidden) (bf16)
    rmsnorm2<float, bf16><<<BS_, 256, 0, stream>>>(hidden, ln1_w, Xb, H_, H_, H_);
    // 2. QAb = Xb @ qaT (bf16)
    gemm_bf16<0, bf16><<<dim3(QL_ / 128, BS_ / 128), 256, 0, stream>>>(
        Xb, qaT, nullptr, nullptr, QAb, BS_, QL_, H_);
    // 3. QAb = rmsnorm(QAb) in place
    rmsnorm2<bf16, bf16><<<BS_, 256, 0, stream>>>(QAb, q_a_ln, QAb, QL_, QL_, QL_);
    // 4. Qb = QAb @ qbT (bf16)
    gemm_bf16<0, bf16><<<dim3((NH_ * QHD_) / 128, BS_ / 128), 256, 0, stream>>>(
        QAb, qbT, nullptr, nullptr, Qb, BS_, NH_ * QHD_, QL_);
    // 5. CKV = Xb @ kvaT (fp32, padded width 640; cols 576..639 are zeros)
    gemm_bf16<0, float><<<dim3(CKVP_ / 128, BS_ / 128), 256, 0, stream>>>(
        Xb, kvaT, nullptr, nullptr, CKV, BS_, CKVP_, H_);
    // 6. CKVNb = rmsnorm(CKV[:, :512]) (bf16)
    rmsnorm2<float, bf16><<<BS_, 256, 0, stream>>>(CKV, kv_a_ln, CKVNb, KVL_, CKVP_, KVL_);
    // 7. KV = CKVNb @ kvbT (fp32)
    gemm_bf16<0, float><<<dim3((NH_ * KVW_) / 128, BS_ / 128), 256, 0, stream>>>(
        CKVNb, kvbT, nullptr, nullptr, KV, BS_, NH_ * KVW_, KVL_);
    // 8. RoPE in place on Qb (bf16) and CKV k_pe (fp32)
    rope_kernel<<<(BS_ * NH_ + BS_) / 4, 256, 0, stream>>>(Qb, CKV, pos, sinT, cosT);
    // 9. attention -> ATTNb (bf16)
    attn_kernel<<<dim3(S_ / 4, NH_, B_), 256, 0, stream>>>(Qb, KV, CKV, ATTNb);
    // 10. d_out = ATTNb @ oT + hidden (fp32)
    gemm_bf16<1, float><<<dim3(H_ / 128, BS_ / 128), 256, 0, stream>>>(
        ATTNb, oT, hidden, nullptr, out, BS_, H_, NH_ * VHD_);

    // 11. MLP-phase weight transposes (overlaying dead attention buffers)
    transp_bf16<<<dim3(8192 / 32, 2048 / 32), tb, 0, stream>>>(gate_k, gateT, 2048, 8192, 8192);
    transp_bf16<<<dim3(8192 / 32, 2048 / 32), tb, 0, stream>>>(up_k, upT, 2048, 8192, 8192);
    transp_bf16<<<dim3(2048 / 32, 8192 / 32), tb, 0, stream>>>(down_k, downT, 8192, 2048, 2048);

    // 12. X2b = rmsnorm(d_out) (bf16)
    rmsnorm2<float, bf16><<<BS_, 256, 0, stream>>>(out, ln2_w, X2b, H_, H_, H_);
    // 13. MLPb = X2b @ gateT (bf16)
    gemm_bf16<0, bf16><<<dim3(FF_ / 128, BS_ / 128), 256, 0, stream>>>(
        X2b, gateT, nullptr, nullptr, MLPb, BS_, FF_, H_);
    // 14. MLPb = silu(MLPb) * (X2b @ upT) (bf16, in place)
    gemm_bf16<2, bf16><<<dim3(FF_ / 128, BS_ / 128), 256, 0, stream>>>(
        X2b, upT, nullptr, MLPb, MLPb, BS_, FF_, H_);
    // 15. d_out = MLPb @ downT + d_out (fp32, in place)
    gemm_bf16<1, float><<<dim3(H_ / 128, BS_ / 128), 256, 0, stream>>>(
        MLPb, downT, out, nullptr, out, BS_, H_, FF_);
}

// Round 3
// 1291.385 us; speedup vs baseline: 14.5127x; 6.2605x over previous
//
#include <hip/hip_runtime.h>
#include <hip/hip_bf16.h>
#include <cstdint>

#define B_ 2
#define S_ 2048
#define H_ 2048
#define NH_ 16
#define QL_ 1536
#define KVL_ 512
#define NOPE_ 128
#define ROPE_ 64
#define QHD_ 192
#define VHD_ 128
#define FF_ 8192
#define BS_ (B_ * S_)            // 4096 rows
#define CKVP_ 640                // padded ckv width (576 -> 640 for N%128==0)
#define KVW_ (NOPE_ + VHD_)      // 256 per head

typedef __hip_bfloat16 bf16;
typedef __attribute__((ext_vector_type(8))) short short8_t;  // 8 bf16 (4 VGPRs)
typedef __attribute__((ext_vector_type(4))) float f32x4;

__device__ __forceinline__ float ldf(const float* p, size_t i) { return p[i]; }
__device__ __forceinline__ float ldf(const bf16* p, size_t i) { return __bfloat162float(p[i]); }
__device__ __forceinline__ void stf(float* p, size_t i, float v) { p[i] = v; }
__device__ __forceinline__ void stf(bf16* p, size_t i, float v) { p[i] = __float2bfloat16(v); }

// ---------------------------------------------------------------------------
// Transpose + convert: in fp32 [K][N] -> out bf16 [Npad][K]; rows n>=N zeroed.
// ---------------------------------------------------------------------------
__global__ __launch_bounds__(256) void transp_bf16(
    const float* __restrict__ in, bf16* __restrict__ out, int K, int N, int Npad)
{
    __shared__ float t[32][33];
    const int n0 = blockIdx.x * 32, k0 = blockIdx.y * 32;
    for (int r = threadIdx.y; r < 32; r += 8) {
        const int n = n0 + threadIdx.x;
        t[r][threadIdx.x] = (n < N) ? in[(size_t)(k0 + r) * N + n] : 0.f;
    }
    __syncthreads();
    for (int r = threadIdx.y; r < 32; r += 8) {
        out[(size_t)(n0 + r) * K + k0 + threadIdx.x] = __float2bfloat16(t[threadIdx.x][r]);
    }
}

// ---------------------------------------------------------------------------
// RMSNorm (templated dtypes): one 256-thread block per row.
// ---------------------------------------------------------------------------
template<typename InT, typename OutT>
__global__ __launch_bounds__(256) void rmsnorm2(
    const InT* __restrict__ in, const float* __restrict__ w,
    OutT* __restrict__ out, int cols, int istride, int ostride)
{
    const int row = blockIdx.x;
    const InT* ip = in + (size_t)row * istride;
    OutT* op = out + (size_t)row * ostride;

    float ss = 0.f;
    for (int c = threadIdx.x; c < cols; c += 256) {
        float v = ldf(ip, c);
        ss = fmaf(v, v, ss);
    }
    #pragma unroll
    for (int off = 32; off; off >>= 1) ss += __shfl_xor(ss, off);
    __shared__ float red[4];
    if ((threadIdx.x & 63) == 0) red[threadIdx.x >> 6] = ss;
    __syncthreads();
    const float total = red[0] + red[1] + red[2] + red[3];
    const float scale = rsqrtf(total / (float)cols + 1e-6f);
    for (int c = threadIdx.x; c < cols; c += 256) {
        stf(op, c, ldf(ip, c) * scale * w[c]);
    }
}

// ---------------------------------------------------------------------------
// bf16 MFMA GEMM (m97 structure): C[M][N] = A[M][K] @ BT[N][K]^T
// ---------------------------------------------------------------------------
__device__ __forceinline__ void gload16(const void* g, void* l)
{
    __builtin_amdgcn_global_load_lds((const unsigned int*)g, (unsigned int*)l, 16, 0, 0);
}

template<int MODE, typename OutT>
__global__ __launch_bounds__(256) void gemm_bf16(
    const bf16* __restrict__ A, const bf16* __restrict__ BT,
    const float* __restrict__ Df, const bf16* __restrict__ Db,
    OutT* __restrict__ C, int M, int N, int K)
{
    __shared__ short As[128 * 32];
    __shared__ short Bs[128 * 32];
    const int tid = threadIdx.x;
    const int wid = tid >> 6, lane = tid & 63;
    const int bm = blockIdx.y * 128, bn = blockIdx.x * 128;
    const int wr = (wid >> 1) * 64, wc = (wid & 1) * 64;
    const int l16 = lane & 15;
    const int lk = (lane >> 4) << 3;

    f32x4 acc[4][4] = {};

    for (int k0 = 0; k0 < K; k0 += 32) {
        #pragma unroll
        for (int is = 0; is < 2; ++is) {
            const int c = is * 256 + tid;
            const int row = c >> 2;
            const int cb = (c & 3) * 16;
            const char* srcA = (const char*)A + ((size_t)(bm + row) * K + k0) * 2 + cb;
            const char* srcB = (const char*)BT + ((size_t)(bn + row) * K + k0) * 2 + cb;
            char* dstA = (char*)As + (is * 256 + wid * 64) * 16;
            char* dstB = (char*)Bs + (is * 256 + wid * 64) * 16;
            gload16(srcA, dstA);
            gload16(srcB, dstB);
        }
        __syncthreads();

        short8_t a[4], b[4];
        const short* ApW = As + (wr + l16) * 32 + lk;
        const short* BpW = Bs + (wc + l16) * 32 + lk;
        #pragma unroll
        for (int m = 0; m < 4; ++m) a[m] = *(const short8_t*)(ApW + m * 16 * 32);
        #pragma unroll
        for (int n = 0; n < 4; ++n) b[n] = *(const short8_t*)(BpW + n * 16 * 32);
        #pragma unroll
        for (int m = 0; m < 4; ++m)
            #pragma unroll
            for (int n = 0; n < 4; ++n)
                acc[m][n] = __builtin_amdgcn_mfma_f32_16x16x32_bf16(a[m], b[n], acc[m][n], 0, 0, 0);
        __syncthreads();
    }

    const int r0 = bm + wr + ((lane >> 4) << 2);
    const int c0 = bn + wc + l16;
    #pragma unroll
    for (int m = 0; m < 4; ++m) {
        #pragma unroll
        for (int n = 0; n < 4; ++n) {
            const int row = r0 + m * 16;
            const int col = c0 + n * 16;
            #pragma unroll
            for (int r = 0; r < 4; ++r) {
                const size_t off = (size_t)(row + r) * N + col;
                float v = acc[m][n][r];
                if (MODE == 1) v += Df[off];
                if (MODE == 2) {
                    const float g = __bfloat162float(Db[off]);
                    v *= g / (1.f + __expf(-g));
                }
                stf(C, off, v);
            }
        }
    }
}

// ---------------------------------------------------------------------------
// RoPE: one wave per 64-dim slice. q bf16 (B,S,NH,192), k_pe fp32 in ckv.
// ---------------------------------------------------------------------------
__global__ __launch_bounds__(256) void rope_kernel(
    bf16* __restrict__ q, float* __restrict__ ckv,
    const int* __restrict__ pos_ids,
    const float* __restrict__ sinT, const float* __restrict__ cosT)
{
    const int wid = blockIdx.x * 4 + (threadIdx.x >> 6);
    const int lane = threadIdx.x & 63;
    const int NQ = BS_ * NH_;

    int bs;
    bf16* bptr = nullptr;
    float* fptr = nullptr;
    if (wid < NQ) {
        bs = wid >> 4;
        bptr = q + (size_t)wid * QHD_ + NOPE_;
    } else {
        bs = wid - NQ;
        fptr = ckv + (size_t)bs * CKVP_ + KVL_;
    }
    const int pos = pos_ids[bs];
    const float c  = cosT[pos * ROPE_ + lane];
    const float sn = sinT[pos * ROPE_ + lane];
    const float x = bptr ? __bfloat162float(bptr[lane]) : fptr[lane];
    const int j = lane & 31;
    const float x0 = __shfl(x, 2 * j);
    const float x1 = __shfl(x, 2 * j + 1);
    const float res = (lane < 32) ? fmaf(x0, c, -x1 * sn) : fmaf(x1, c, x0 * sn);
    if (bptr) bptr[lane] = __float2bfloat16(res);
    else      fptr[lane] = res;
}

// ---------------------------------------------------------------------------
// pack_k: Kh (B,NH,S,192) bf16 <- k_nope from KV fp32 + rope'd k_pe from CKV.
// ---------------------------------------------------------------------------
__global__ __launch_bounds__(256) void pack_k(
    const float* __restrict__ KV, const float* __restrict__ CKV,
    bf16* __restrict__ Kh)
{
    const int total = BS_ * NH_ * (QHD_ / 2);
    for (int i = blockIdx.x * 256 + threadIdx.x; i < total; i += gridDim.x * 256) {
        const int d2 = i % (QHD_ / 2);
        const int t  = i / (QHD_ / 2);
        const int s  = t % S_;
        const int hh = (t / S_) % NH_;
        const int bb = t / (S_ * NH_);
        const int d = d2 * 2;
        float2 v;
        if (d < NOPE_) v = *(const float2*)&KV[(((size_t)bb * S_ + s) * NH_ + hh) * KVW_ + d];
        else           v = *(const float2*)&CKV[((size_t)bb * S_ + s) * CKVP_ + KVL_ + (d - NOPE_)];
        union { bf16 h[2]; unsigned int u; } cv;
        cv.h[0] = __float2bfloat16(v.x);
        cv.h[1] = __float2bfloat16(v.y);
        *(unsigned int*)&Kh[((size_t)(bb * NH_ + hh) * S_ + s) * QHD_ + d] = cv.u;
    }
}

// ---------------------------------------------------------------------------
// pack_vt: Vt (B,NH,128,S) bf16 <- V = KV[...,128:256] fp32, transposed.
// ---------------------------------------------------------------------------
__global__ __launch_bounds__(256) void pack_vt(
    const float* __restrict__ KV, bf16* __restrict__ Vt)
{
    __shared__ float t[32][33];
    const int s0 = blockIdx.x * 32, d0 = blockIdx.y * 32;
    const int bh = blockIdx.z;
    const int tx = threadIdx.x & 31, ty = threadIdx.x >> 5;
    for (int r = ty; r < 32; r += 8)
        t[r][tx] = KV[(((size_t)(bh >> 4) * S_ + s0 + r) * NH_ + (bh & 15)) * KVW_ + NOPE_ + d0 + tx];
    __syncthreads();
    for (int r = ty; r < 32; r += 8)
        Vt[((size_t)bh * VHD_ + d0 + r) * S_ + s0 + tx] = __float2bfloat16(t[tx][r]);
}

// ---------------------------------------------------------------------------
// MFMA flash attention. Block = (b,h,64 q-rows), 4 waves x 16 q-rows.
// Qp (B,S,NH,192) bf16 (rope'd); Kh (B,NH,S,192) bf16; Vt (B,NH,128,S) bf16.
// out (B,S,NH,128) bf16.
// ---------------------------------------------------------------------------
__global__ __launch_bounds__(256) void attn_mfma(
    const bf16* __restrict__ Qp, const bf16* __restrict__ Kh,
    const bf16* __restrict__ Vt, bf16* __restrict__ outp)
{
    __shared__ short Ks[64][200];     // 64 keys x 192 (+8 pad)
    __shared__ short Vs[128][72];     // V^T: 128 d x 64 keys (+8 pad)
    __shared__ short Ps[4][16][72];   // per-wave P: 16 q x 64 keys (+8 pad)

    const int tid = threadIdx.x;
    const int wid = tid >> 6, lane = tid & 63;
    const int l16 = lane & 15;
    const int lk  = (lane >> 4) << 3;   // {0,8,16,24}
    const int pr  = (lane >> 4) << 2;   // {0,4,8,12}
    const int q0 = blockIdx.x * 64;
    const int h = blockIdx.y, b = blockIdx.z;
    const int qw = q0 + wid * 16;

    // Q fragments (A-layout: row=l16, k=lk+j), 6 k-steps of 32
    short8_t qf[6];
    const bf16* qbase = Qp + (((size_t)b * S_ + qw + l16) * NH_ + h) * QHD_;
    #pragma unroll
    for (int kk = 0; kk < 6; ++kk)
        qf[kk] = *(const short8_t*)(qbase + kk * 32 + lk);

    const bf16* Khb = Kh + (size_t)(b * NH_ + h) * S_ * QHD_;
    const bf16* Vtb = Vt + (size_t)(b * NH_ + h) * VHD_ * S_;

    f32x4 o[8] = {};
    float mr[4] = {-3.0e38f, -3.0e38f, -3.0e38f, -3.0e38f};
    float lr[4] = {0.f, 0.f, 0.f, 0.f};
    const float scale = 0.07216878364870323f;  // 192^-0.5

    const int krow = tid >> 2, kpart = tid & 3;   // K staging: 4 thr/row, 96B each
    const int vrow = tid >> 1, vpart = tid & 1;   // V staging: 2 thr/row, 64B each

    for (int k0 = 0; k0 <= q0; k0 += 64) {
        // ---- stage K tile (reg -> LDS, padded rows) ----
        {
            const short* src = (const short*)(Khb + (size_t)(k0 + krow) * QHD_) + kpart * 48;
            short8_t t0 = *(const short8_t*)(src);
            short8_t t1 = *(const short8_t*)(src + 8);
            short8_t t2 = *(const short8_t*)(src + 16);
            short8_t t3 = *(const short8_t*)(src + 24);
            short8_t t4 = *(const short8_t*)(src + 32);
            short8_t t5 = *(const short8_t*)(src + 40);
            short* d = &Ks[krow][kpart * 48];
            *(short8_t*)(d) = t0; *(short8_t*)(d + 8) = t1; *(short8_t*)(d + 16) = t2;
            *(short8_t*)(d + 24) = t3; *(short8_t*)(d + 32) = t4; *(short8_t*)(d + 40) = t5;
        }
        // ---- stage V^T tile ----
        {
            const short* src = (const short*)(Vtb + (size_t)vrow * S_ + k0) + vpart * 32;
            short8_t t0 = *(const short8_t*)(src);
            short8_t t1 = *(const short8_t*)(src + 8);
            short8_t t2 = *(const short8_t*)(src + 16);
            short8_t t3 = *(const short8_t*)(src + 24);
            short* d = &Vs[vrow][vpart * 32];
            *(short8_t*)(d) = t0; *(short8_t*)(d + 8) = t1;
            *(short8_t*)(d + 16) = t2; *(short8_t*)(d + 24) = t3;
        }
        __syncthreads();

        // ---- QK^T: S[16q x 64k] ----
        f32x4 s[4] = {};
        #pragma unroll
        for (int kk = 0; kk < 6; ++kk) {
            #pragma unroll
            for (int n = 0; n < 4; ++n) {
                short8_t kf = *(const short8_t*)&Ks[n * 16 + l16][kk * 32 + lk];
                s[n] = __builtin_amdgcn_mfma_f32_16x16x32_bf16(qf[kk], kf, s[n], 0, 0, 0);
            }
        }
        // ---- causal mask (C layout: row=pr+r, col=n*16+l16) ----
        #pragma unroll
        for (int n = 0; n < 4; ++n) {
            const int kg = k0 + n * 16 + l16;
            #pragma unroll
            for (int r = 0; r < 4; ++r) {
                if (kg > qw + pr + r) s[n][r] = -3.0e38f;
            }
        }
        // ---- online softmax (scale folded into exp arg) ----
        float pexp[4][4];
        #pragma unroll
        for (int r = 0; r < 4; ++r) {
            float rm = fmaxf(fmaxf(s[0][r], s[1][r]), fmaxf(s[2][r], s[3][r]));
            rm = fmaxf(rm, __shfl_xor(rm, 1));
            rm = fmaxf(rm, __shfl_xor(rm, 2));
            rm = fmaxf(rm, __shfl_xor(rm, 4));
            rm = fmaxf(rm, __shfl_xor(rm, 8));
            const float mnew = fmaxf(mr[r], rm);
            const float corr = __expf((mr[r] - mnew) * scale);
            mr[r] = mnew;
            float rs = 0.f;
            #pragma unroll
            for (int n = 0; n < 4; ++n) {
                const float p = __expf((s[n][r] - mnew) * scale);
                pexp[n][r] = p;
                rs += p;
            }
            rs += __shfl_xor(rs, 1);
            rs += __shfl_xor(rs, 2);
            rs += __shfl_xor(rs, 4);
            rs += __shfl_xor(rs, 8);
            lr[r] = lr[r] * corr + rs;
            #pragma unroll
            for (int n = 0; n < 8; ++n) o[n][r] *= corr;
        }
        // ---- P -> LDS (bf16) ----
        #pragma unroll
        for (int n = 0; n < 4; ++n) {
            #pragma unroll
            for (int r = 0; r < 4; ++r) {
                union { bf16 hh; short u; } cv;
                cv.hh = __float2bfloat16(pexp[n][r]);
                Ps[wid][pr + r][n * 16 + l16] = cv.u;
            }
        }
        // ---- PV: O += P[16x64] @ V[64x128] ----
        #pragma unroll
        for (int kk2 = 0; kk2 < 2; ++kk2) {
            short8_t pf = *(const short8_t*)&Ps[wid][l16][kk2 * 32 + lk];
            #pragma unroll
            for (int n = 0; n < 8; ++n) {
                short8_t vf = *(const short8_t*)&Vs[n * 16 + l16][kk2 * 32 + lk];
                o[n] = __builtin_amdgcn_mfma_f32_16x16x32_bf16(pf, vf, o[n], 0, 0, 0);
            }
        }
        __syncthreads();
    }

    // ---- epilogue ----
    float inv[4];
    #pragma unroll
    for (int r = 0; r < 4; ++r) inv[r] = 1.f / lr[r];
    bf16* ob = outp + (((size_t)b * S_ + qw + pr) * NH_ + h) * VHD_;
    #pragma unroll
    for (int r = 0; r < 4; ++r)
        #pragma unroll
        for (int n = 0; n < 8; ++n)
            ob[(size_t)r * (NH_ * VHD_) + n * 16 + l16] = __float2bfloat16(o[n][r] * inv[r]);
}

// ---------------------------------------------------------------------------
// Launch
// ---------------------------------------------------------------------------
extern "C" void kernel_launch(void* const* d_in, const int* in_sizes, int n_in,
                              void* d_out, int out_size, void* d_ws, size_t ws_size,
                              hipStream_t stream)
{
    const float* hidden  = (const float*)d_in[0];
    const float* ln1_w   = (const float*)d_in[1];
    const float* q_a_k   = (const float*)d_in[2];
    const float* q_a_ln  = (const float*)d_in[3];
    const float* q_b_k   = (const float*)d_in[4];
    const float* kv_a_k  = (const float*)d_in[5];
    const float* kv_a_ln = (const float*)d_in[6];
    const float* kv_b_k  = (const float*)d_in[7];
    const float* o_k     = (const float*)d_in[8];
    const float* ln2_w   = (const float*)d_in[9];
    const float* gate_k  = (const float*)d_in[10];
    const float* up_k    = (const float*)d_in[11];
    const float* down_k  = (const float*)d_in[12];
    const float* sinT    = (const float*)d_in[13];
    const float* cosT    = (const float*)d_in[14];
    const int*   pos     = (const int*)d_in[15];
    float* out = (float*)d_out;
    char* ws = (char*)d_ws;

    // ---- Phase-1 workspace layout (bytes) — peak 184.0 MB ----
    bf16* qaT   = (bf16*)(ws + 0);            // [1536][2048]  6,291,456
    bf16* qbT   = (bf16*)(ws + 6291456);      // [3072][1536]  9,437,184
    bf16* kvaT  = (bf16*)(ws + 15728640);     // [640][2048]   2,621,440
    bf16* kvbT  = (bf16*)(ws + 18350080);     // [4096][512]   4,194,304
    bf16* oT    = (bf16*)(ws + 22544384);     // [2048][2048]  8,388,608
    bf16* Xb    = (bf16*)(ws + 30932992);     // [4096][2048] 16,777,216
    bf16* QAb   = (bf16*)(ws + 47710208);     // [4096][1536] 12,582,912
    bf16* CKVNb = (bf16*)(ws + 60293120);     // [4096][512]   4,194,304
    bf16* Qb    = (bf16*)(ws + 64487424);     // [4096][3072] 25,165,824
    float* CKV  = (float*)(ws + 89653248);    // [4096][640]  10,485,760
    float* KV   = (float*)(ws + 100139008);   // [4096][4096] 67,108,864
    bf16* ATTNb = (bf16*)(ws + 167247872);    // [4096][2048] 16,777,216
    // pack buffers overlay dead phase-1 regions:
    bf16* Vt    = (bf16*)(ws + 0);            // (B,NH,128,S) 16,777,216 over qaT/qbT/kvaT (dead)
    bf16* Kh    = (bf16*)(ws + 30932992);     // (B,NH,S,192) 25,165,824 over Xb+QAb (dead)
    // ---- Phase-2 layout (after o-GEMM) — peak 184.5 MB ----
    bf16* gateT = (bf16*)(ws + 0);            // [8192][2048] 33,554,432
    bf16* upT   = (bf16*)(ws + 33554432);     // [8192][2048] 33,554,432
    bf16* downT = (bf16*)(ws + 67108864);     // [2048][8192] 33,554,432
    bf16* X2b   = (bf16*)(ws + 100663296);    // [4096][2048] 16,777,216
    bf16* MLPb  = (bf16*)(ws + 117440512);    // [4096][8192] 67,108,864

    const dim3 tb(32, 8);

    // 0. weight transposes (attention-phase weights)
    transp_bf16<<<dim3(1536 / 32, 2048 / 32), tb, 0, stream>>>(q_a_k, qaT, 2048, 1536, 1536);
    transp_bf16<<<dim3(3072 / 32, 1536 / 32), tb, 0, stream>>>(q_b_k, qbT, 1536, 3072, 3072);
    transp_bf16<<<dim3(640 / 32, 2048 / 32), tb, 0, stream>>>(kv_a_k, kvaT, 2048, 576, 640);
    transp_bf16<<<dim3(4096 / 32, 512 / 32), tb, 0, stream>>>(kv_b_k, kvbT, 512, 4096, 4096);
    transp_bf16<<<dim3(2048 / 32, 2048 / 32), tb, 0, stream>>>(o_k, oT, 2048, 2048, 2048);

    // 1. Xb = rmsnorm(hidden)
    rmsnorm2<float, bf16><<<BS_, 256, 0, stream>>>(hidden, ln1_w, Xb, H_, H_, H_);
    // 2. QAb = Xb @ qaT
    gemm_bf16<0, bf16><<<dim3(QL_ / 128, BS_ / 128), 256, 0, stream>>>(
        Xb, qaT, nullptr, nullptr, QAb, BS_, QL_, H_);
    // 3. QAb = rmsnorm(QAb) in place
    rmsnorm2<bf16, bf16><<<BS_, 256, 0, stream>>>(QAb, q_a_ln, QAb, QL_, QL_, QL_);
    // 4. Qb = QAb @ qbT
    gemm_bf16<0, bf16><<<dim3((NH_ * QHD_) / 128, BS_ / 128), 256, 0, stream>>>(
        QAb, qbT, nullptr, nullptr, Qb, BS_, NH_ * QHD_, QL_);
    // 5. CKV = Xb @ kvaT (fp32, padded width 640)
    gemm_bf16<0, float><<<dim3(CKVP_ / 128, BS_ / 128), 256, 0, stream>>>(
        Xb, kvaT, nullptr, nullptr, CKV, BS_, CKVP_, H_);
    // 6. CKVNb = rmsnorm(CKV[:, :512])
    rmsnorm2<float, bf16><<<BS_, 256, 0, stream>>>(CKV, kv_a_ln, CKVNb, KVL_, CKVP_, KVL_);
    // 7. KV = CKVNb @ kvbT (fp32)
    gemm_bf16<0, float><<<dim3((NH_ * KVW_) / 128, BS_ / 128), 256, 0, stream>>>(
        CKVNb, kvbT, nullptr, nullptr, KV, BS_, NH_ * KVW_, KVL_);
    // 8. RoPE in place on Qb and CKV k_pe
    rope_kernel<<<(BS_ * NH_ + BS_) / 4, 256, 0, stream>>>(Qb, CKV, pos, sinT, cosT);
    // 9. pack K and V^T into head-major bf16
    pack_k<<<2048, 256, 0, stream>>>(KV, CKV, Kh);
    pack_vt<<<dim3(S_ / 32, VHD_ / 32, B_ * NH_), 256, 0, stream>>>(KV, Vt);
    // 10. MFMA flash attention -> ATTNb
    attn_mfma<<<dim3(S_ / 64, NH_, B_), 256, 0, stream>>>(Qb, Kh, Vt, ATTNb);
    // 11. d_out = ATTNb @ oT + hidden (fp32)
    gemm_bf16<1, float><<<dim3(H_ / 128, BS_ / 128), 256, 0, stream>>>(
        ATTNb, oT, hidden, nullptr, out, BS_, H_, NH_ * VHD_);

    // 12. MLP-phase weight transposes (overlay dead attention buffers)
    transp_bf16<<<dim3(8192 / 32, 2048 / 32), tb, 0, stream>>>(gate_k, gateT, 2048, 8192, 8192);
    transp_bf16<<<dim3(8192 / 32, 2048 / 32), tb, 0, stream>>>(up_k, upT, 2048, 8192, 8192);
    transp_bf16<<<dim3(2048 / 32, 8192 / 32), tb, 0, stream>>>(down_k, downT, 8192, 2048, 2048);

    // 13. X2b = rmsnorm(d_out)
    rmsnorm2<float, bf16><<<BS_, 256, 0, stream>>>(out, ln2_w, X2b, H_, H_, H_);
    // 14. MLPb = X2b @ gateT
    gemm_bf16<0, bf16><<<dim3(FF_ / 128, BS_ / 128), 256, 0, stream>>>(
        X2b, gateT, nullptr, nullptr, MLPb, BS_, FF_, H_);
    // 15. MLPb = silu(MLPb) * (X2b @ upT)
    gemm_bf16<2, bf16><<<dim3(FF_ / 128, BS_ / 128), 256, 0, stream>>>(
        X2b, upT, nullptr, MLPb, MLPb, BS_, FF_, H_);
    // 16. d_out = MLPb @ downT + d_out
    gemm_bf16<1, float><<<dim3(H_ / 128, BS_ / 128), 256, 0, stream>>>(
        MLPb, downT, out, nullptr, out, BS_, H_, FF_);
}

// Round 4
// 1161.497 us; speedup vs baseline: 16.1357x; 1.1118x over previous
//
#include <hip/hip_runtime.h>
#include <hip/hip_bf16.h>
#include <cstdint>

#define B_ 2
#define S_ 2048
#define H_ 2048
#define NH_ 16
#define QL_ 1536
#define KVL_ 512
#define NOPE_ 128
#define ROPE_ 64
#define QHD_ 192
#define VHD_ 128
#define FF_ 8192
#define BS_ (B_ * S_)            // 4096 rows
#define CKVP_ 640                // padded ckv width (576 -> 640 for N%128==0)
#define KVW_ (NOPE_ + VHD_)      // 256 per head

typedef __hip_bfloat16 bf16;
typedef __attribute__((ext_vector_type(8))) short short8_t;  // 8 bf16 (4 VGPRs)
typedef __attribute__((ext_vector_type(4))) float f32x4;

__device__ __forceinline__ float ldf(const float* p, size_t i) { return p[i]; }
__device__ __forceinline__ float ldf(const bf16* p, size_t i) { return __bfloat162float(p[i]); }
__device__ __forceinline__ void stf(float* p, size_t i, float v) { p[i] = v; }
__device__ __forceinline__ void stf(bf16* p, size_t i, float v) { p[i] = __float2bfloat16(v); }

__device__ __forceinline__ void gload16(const void* g, void* l)
{
    __builtin_amdgcn_global_load_lds((const unsigned int*)g, (unsigned int*)l, 16, 0, 0);
}

// ---------------------------------------------------------------------------
// Transpose + convert: in fp32 [K][N] -> out bf16 [Npad][K]; rows n>=N zeroed.
// ---------------------------------------------------------------------------
__global__ __launch_bounds__(256) void transp_bf16(
    const float* __restrict__ in, bf16* __restrict__ out, int K, int N, int Npad)
{
    __shared__ float t[32][33];
    const int n0 = blockIdx.x * 32, k0 = blockIdx.y * 32;
    for (int r = threadIdx.y; r < 32; r += 8) {
        const int n = n0 + threadIdx.x;
        t[r][threadIdx.x] = (n < N) ? in[(size_t)(k0 + r) * N + n] : 0.f;
    }
    __syncthreads();
    for (int r = threadIdx.y; r < 32; r += 8) {
        out[(size_t)(n0 + r) * K + k0 + threadIdx.x] = __float2bfloat16(t[threadIdx.x][r]);
    }
}

// ---------------------------------------------------------------------------
// RMSNorm (templated dtypes): one 256-thread block per row.
// ---------------------------------------------------------------------------
template<typename InT, typename OutT>
__global__ __launch_bounds__(256) void rmsnorm2(
    const InT* __restrict__ in, const float* __restrict__ w,
    OutT* __restrict__ out, int cols, int istride, int ostride)
{
    const int row = blockIdx.x;
    const InT* ip = in + (size_t)row * istride;
    OutT* op = out + (size_t)row * ostride;

    float ss = 0.f;
    for (int c = threadIdx.x; c < cols; c += 256) {
        float v = ldf(ip, c);
        ss = fmaf(v, v, ss);
    }
    #pragma unroll
    for (int off = 32; off; off >>= 1) ss += __shfl_xor(ss, off);
    __shared__ float red[4];
    if ((threadIdx.x & 63) == 0) red[threadIdx.x >> 6] = ss;
    __syncthreads();
    const float total = red[0] + red[1] + red[2] + red[3];
    const float scale = rsqrtf(total / (float)cols + 1e-6f);
    for (int c = threadIdx.x; c < cols; c += 256) {
        stf(op, c, ldf(ip, c) * scale * w[c]);
    }
}

// ---------------------------------------------------------------------------
// 128x128 2-phase GEMM (m97 structure) — used for small-N shapes.
// ---------------------------------------------------------------------------
template<int MODE, typename OutT>
__global__ __launch_bounds__(256) void gemm_bf16(
    const bf16* __restrict__ A, const bf16* __restrict__ BT,
    const float* __restrict__ Df, const bf16* __restrict__ Db,
    OutT* __restrict__ C, int M, int N, int K)
{
    __shared__ short As[128 * 32];
    __shared__ short Bs[128 * 32];
    const int tid = threadIdx.x;
    const int wid = tid >> 6, lane = tid & 63;
    const int bm = blockIdx.y * 128, bn = blockIdx.x * 128;
    const int wr = (wid >> 1) * 64, wc = (wid & 1) * 64;
    const int l16 = lane & 15;
    const int lk = (lane >> 4) << 3;

    f32x4 acc[4][4] = {};

    for (int k0 = 0; k0 < K; k0 += 32) {
        #pragma unroll
        for (int is = 0; is < 2; ++is) {
            const int c = is * 256 + tid;
            const int row = c >> 2;
            const int cb = (c & 3) * 16;
            const char* srcA = (const char*)A + ((size_t)(bm + row) * K + k0) * 2 + cb;
            const char* srcB = (const char*)BT + ((size_t)(bn + row) * K + k0) * 2 + cb;
            char* dstA = (char*)As + (is * 256 + wid * 64) * 16;
            char* dstB = (char*)Bs + (is * 256 + wid * 64) * 16;
            gload16(srcA, dstA);
            gload16(srcB, dstB);
        }
        __syncthreads();

        short8_t a[4], b[4];
        const short* ApW = As + (wr + l16) * 32 + lk;
        const short* BpW = Bs + (wc + l16) * 32 + lk;
        #pragma unroll
        for (int m = 0; m < 4; ++m) a[m] = *(const short8_t*)(ApW + m * 16 * 32);
        #pragma unroll
        for (int n = 0; n < 4; ++n) b[n] = *(const short8_t*)(BpW + n * 16 * 32);
        #pragma unroll
        for (int m = 0; m < 4; ++m)
            #pragma unroll
            for (int n = 0; n < 4; ++n)
                acc[m][n] = __builtin_amdgcn_mfma_f32_16x16x32_bf16(a[m], b[n], acc[m][n], 0, 0, 0);
        __syncthreads();
    }

    const int r0 = bm + wr + ((lane >> 4) << 2);
    const int c0 = bn + wc + l16;
    #pragma unroll
    for (int m = 0; m < 4; ++m) {
        #pragma unroll
        for (int n = 0; n < 4; ++n) {
            const int row = r0 + m * 16;
            const int col = c0 + n * 16;
            #pragma unroll
            for (int r = 0; r < 4; ++r) {
                const size_t off = (size_t)(row + r) * N + col;
                float v = acc[m][n][r];
                if (MODE == 1) v += Df[off];
                if (MODE == 2) {
                    const float g = __bfloat162float(Db[off]);
                    v *= g / (1.f + __expf(-g));
                }
                stf(C, off, v);
            }
        }
    }
}

// ---------------------------------------------------------------------------
// 256x256 8-phase GEMM (m201 template, plain HIP). BK=64, 512 thr = 8 waves
// (2M x 4N), per-wave 128x64. T2 chunk-XOR swizzle (linear gload_lds dest +
// inverse-swizzled global src + swizzled ds_read). T5 setprio around MFMA.
// Single vmcnt(0)+syncthreads per K-tile, issued 3 phases after the loads.
// Requires M%256==0, N%256==0, K%64==0.
// ---------------------------------------------------------------------------
__device__ __forceinline__ short8_t ldsfrag(const short* half_base, int r, int c)
{
    // logical chunk c (8 bf16 = 16B) of row r; physical chunk = c ^ (r&7)
    return *(const short8_t*)(half_base + r * 64 + ((c ^ (r & 7)) << 3));
}

template<int MODE, typename OutT>
__global__ __launch_bounds__(512, 2) void gemm256(
    const bf16* __restrict__ A, const bf16* __restrict__ BT,
    const float* __restrict__ Df, const bf16* __restrict__ Db,
    OutT* __restrict__ C, int M, int N, int K)
{
    __shared__ short lds[2][2][2][128 * 64];   // [buf][A/B][half] = 128 KiB

    const int tid = threadIdx.x;
    const int wid = tid >> 6, lane = tid & 63;
    const int wm = wid >> 2, wn = wid & 3;
    const int l16 = lane & 15, hk = lane >> 4;

    // bijective XCD swizzle (m204)
    const int nwg = gridDim.x * gridDim.y;
    const int orig = blockIdx.y * gridDim.x + blockIdx.x;
    const int q = nwg >> 3, r8 = nwg & 7;
    const int xcd = orig & 7, lid = orig >> 3;
    const int wg = (xcd < r8 ? xcd * (q + 1) : r8 * (q + 1) + (xcd - r8) * q) + lid;
    const int bn = (wg % gridDim.x) * 256;
    const int bm = (wg / gridDim.x) * 256;

    f32x4 acc[8][4] = {};

    const int nt = K >> 6;

    // staging helper (as lambda): stage one 128x64 half into lbase
    auto stage_half = [&](const bf16* gbase, int ldk, short* lbase) {
        #pragma unroll
        for (int i = 0; i < 2; ++i) {
            const int ch = i * 512 + tid;
            const int row = ch >> 3, pc = ch & 7;
            const int gc = pc ^ (row & 7);
            const char* src = (const char*)(gbase + (size_t)row * ldk + gc * 8);
            char* dst = (char*)lbase + (i * 512 + wid * 64) * 16;
            gload16(src, dst);
        }
    };

    // prologue: stage tile 0 into buf 0
    stage_half(A + (size_t)bm * K, K, &lds[0][0][0][0]);
    stage_half(A + (size_t)(bm + 128) * K, K, &lds[0][0][1][0]);
    stage_half(BT + (size_t)bn * K, K, &lds[0][1][0][0]);
    stage_half(BT + (size_t)(bn + 128) * K, K, &lds[0][1][1][0]);
    asm volatile("s_waitcnt vmcnt(0)" ::: "memory");
    __syncthreads();

    int cur = 0;
    for (int t = 0; t < nt; ++t) {
        const int k0n = (t + 1) << 6;
        const short* Ah = &lds[cur][0][wm][0];
        const short* Bh = &lds[cur][1][wn >> 1][0];
        const int brr = (wn & 1) * 64;

        short8_t bfr[4][2], afr[2][2];

        // ---- phase 0: read all B-frags + A-frags(mf 0,1); stage next A ----
        #pragma unroll
        for (int nf = 0; nf < 4; ++nf)
            #pragma unroll
            for (int ks = 0; ks < 2; ++ks)
                bfr[nf][ks] = ldsfrag(Bh, brr + nf * 16 + l16, ks * 4 + hk);
        #pragma unroll
        for (int mi = 0; mi < 2; ++mi)
            #pragma unroll
            for (int ks = 0; ks < 2; ++ks)
                afr[mi][ks] = ldsfrag(Ah, mi * 16 + l16, ks * 4 + hk);
        if (t + 1 < nt) {
            stage_half(A + (size_t)bm * K + k0n, K, &lds[cur ^ 1][0][0][0]);
            stage_half(A + (size_t)(bm + 128) * K + k0n, K, &lds[cur ^ 1][0][1][0]);
        }
        __builtin_amdgcn_s_barrier();
        __builtin_amdgcn_s_setprio(1);
        #pragma unroll
        for (int mi = 0; mi < 2; ++mi)
            #pragma unroll
            for (int nf = 0; nf < 4; ++nf)
                #pragma unroll
                for (int ks = 0; ks < 2; ++ks)
                    acc[mi][nf] = __builtin_amdgcn_mfma_f32_16x16x32_bf16(
                        afr[mi][ks], bfr[nf][ks], acc[mi][nf], 0, 0, 0);
        __builtin_amdgcn_s_setprio(0);
        __builtin_amdgcn_s_barrier();

        // ---- phase 1: A-frags(mf 2,3); stage next B ----
        #pragma unroll
        for (int mi = 0; mi < 2; ++mi)
            #pragma unroll
            for (int ks = 0; ks < 2; ++ks)
                afr[mi][ks] = ldsfrag(Ah, 32 + mi * 16 + l16, ks * 4 + hk);
        if (t + 1 < nt) {
            stage_half(BT + (size_t)bn * K + k0n, K, &lds[cur ^ 1][1][0][0]);
            stage_half(BT + (size_t)(bn + 128) * K + k0n, K, &lds[cur ^ 1][1][1][0]);
        }
        __builtin_amdgcn_s_barrier();
        __builtin_amdgcn_s_setprio(1);
        #pragma unroll
        for (int mi = 0; mi < 2; ++mi)
            #pragma unroll
            for (int nf = 0; nf < 4; ++nf)
                #pragma unroll
                for (int ks = 0; ks < 2; ++ks)
                    acc[2 + mi][nf] = __builtin_amdgcn_mfma_f32_16x16x32_bf16(
                        afr[mi][ks], bfr[nf][ks], acc[2 + mi][nf], 0, 0, 0);
        __builtin_amdgcn_s_setprio(0);
        __builtin_amdgcn_s_barrier();

        // ---- phase 2: A-frags(mf 4,5) ----
        #pragma unroll
        for (int mi = 0; mi < 2; ++mi)
            #pragma unroll
            for (int ks = 0; ks < 2; ++ks)
                afr[mi][ks] = ldsfrag(Ah, 64 + mi * 16 + l16, ks * 4 + hk);
        __builtin_amdgcn_s_barrier();
        __builtin_amdgcn_s_setprio(1);
        #pragma unroll
        for (int mi = 0; mi < 2; ++mi)
            #pragma unroll
            for (int nf = 0; nf < 4; ++nf)
                #pragma unroll
                for (int ks = 0; ks < 2; ++ks)
                    acc[4 + mi][nf] = __builtin_amdgcn_mfma_f32_16x16x32_bf16(
                        afr[mi][ks], bfr[nf][ks], acc[4 + mi][nf], 0, 0, 0);
        __builtin_amdgcn_s_setprio(0);
        __builtin_amdgcn_s_barrier();

        // ---- phase 3: A-frags(mf 6,7); then tile-boundary drain ----
        #pragma unroll
        for (int mi = 0; mi < 2; ++mi)
            #pragma unroll
            for (int ks = 0; ks < 2; ++ks)
                afr[mi][ks] = ldsfrag(Ah, 96 + mi * 16 + l16, ks * 4 + hk);
        __builtin_amdgcn_s_barrier();
        __builtin_amdgcn_s_setprio(1);
        #pragma unroll
        for (int mi = 0; mi < 2; ++mi)
            #pragma unroll
            for (int nf = 0; nf < 4; ++nf)
                #pragma unroll
                for (int ks = 0; ks < 2; ++ks)
                    acc[6 + mi][nf] = __builtin_amdgcn_mfma_f32_16x16x32_bf16(
                        afr[mi][ks], bfr[nf][ks], acc[6 + mi][nf], 0, 0, 0);
        __builtin_amdgcn_s_setprio(0);
        asm volatile("s_waitcnt vmcnt(0)" ::: "memory");
        __syncthreads();
        cur ^= 1;
    }

    // ---- epilogue ----
    const int r0 = bm + wm * 128 + (lane >> 4) * 4;
    const int c0 = bn + wn * 64 + l16;
    #pragma unroll
    for (int mf = 0; mf < 8; ++mf) {
        #pragma unroll
        for (int nf = 0; nf < 4; ++nf) {
            const int row = r0 + mf * 16;
            const int col = c0 + nf * 16;
            #pragma unroll
            for (int r = 0; r < 4; ++r) {
                const size_t off = (size_t)(row + r) * N + col;
                float v = acc[mf][nf][r];
                if (MODE == 1) v += Df[off];
                if (MODE == 2) {
                    const float g = __bfloat162float(Db[off]);
                    v *= g / (1.f + __expf(-g));
                }
                stf(C, off, v);
            }
        }
    }
}

// ---------------------------------------------------------------------------
// RoPE: one wave per 64-dim slice. q bf16 (B,S,NH,192), k_pe fp32 in ckv.
// ---------------------------------------------------------------------------
__global__ __launch_bounds__(256) void rope_kernel(
    bf16* __restrict__ q, float* __restrict__ ckv,
    const int* __restrict__ pos_ids,
    const float* __restrict__ sinT, const float* __restrict__ cosT)
{
    const int wid = blockIdx.x * 4 + (threadIdx.x >> 6);
    const int lane = threadIdx.x & 63;
    const int NQ = BS_ * NH_;

    int bs;
    bf16* bptr = nullptr;
    float* fptr = nullptr;
    if (wid < NQ) {
        bs = wid >> 4;
        bptr = q + (size_t)wid * QHD_ + NOPE_;
    } else {
        bs = wid - NQ;
        fptr = ckv + (size_t)bs * CKVP_ + KVL_;
    }
    const int pos = pos_ids[bs];
    const float c  = cosT[pos * ROPE_ + lane];
    const float sn = sinT[pos * ROPE_ + lane];
    const float x = bptr ? __bfloat162float(bptr[lane]) : fptr[lane];
    const int j = lane & 31;
    const float x0 = __shfl(x, 2 * j);
    const float x1 = __shfl(x, 2 * j + 1);
    const float res = (lane < 32) ? fmaf(x0, c, -x1 * sn) : fmaf(x1, c, x0 * sn);
    if (bptr) bptr[lane] = __float2bfloat16(res);
    else      fptr[lane] = res;
}

// ---------------------------------------------------------------------------
// pack_k: Kh (B,NH,S,192) bf16 <- k_nope from KV fp32 + rope'd k_pe from CKV.
// ---------------------------------------------------------------------------
__global__ __launch_bounds__(256) void pack_k(
    const float* __restrict__ KV, const float* __restrict__ CKV,
    bf16* __restrict__ Kh)
{
    const int total = BS_ * NH_ * (QHD_ / 2);
    for (int i = blockIdx.x * 256 + threadIdx.x; i < total; i += gridDim.x * 256) {
        const int d2 = i % (QHD_ / 2);
        const int t  = i / (QHD_ / 2);
        const int s  = t % S_;
        const int hh = (t / S_) % NH_;
        const int bb = t / (S_ * NH_);
        const int d = d2 * 2;
        float2 v;
        if (d < NOPE_) v = *(const float2*)&KV[(((size_t)bb * S_ + s) * NH_ + hh) * KVW_ + d];
        else           v = *(const float2*)&CKV[((size_t)bb * S_ + s) * CKVP_ + KVL_ + (d - NOPE_)];
        union { bf16 h[2]; unsigned int u; } cv;
        cv.h[0] = __float2bfloat16(v.x);
        cv.h[1] = __float2bfloat16(v.y);
        *(unsigned int*)&Kh[((size_t)(bb * NH_ + hh) * S_ + s) * QHD_ + d] = cv.u;
    }
}

// ---------------------------------------------------------------------------
// pack_vt: Vt (B,NH,128,S) bf16 <- V = KV[...,128:256] fp32, transposed.
// ---------------------------------------------------------------------------
__global__ __launch_bounds__(256) void pack_vt(
    const float* __restrict__ KV, bf16* __restrict__ Vt)
{
    __shared__ float t[32][33];
    const int s0 = blockIdx.x * 32, d0 = blockIdx.y * 32;
    const int bh = blockIdx.z;
    const int tx = threadIdx.x & 31, ty = threadIdx.x >> 5;
    for (int r = ty; r < 32; r += 8)
        t[r][tx] = KV[(((size_t)(bh >> 4) * S_ + s0 + r) * NH_ + (bh & 15)) * KVW_ + NOPE_ + d0 + tx];
    __syncthreads();
    for (int r = ty; r < 32; r += 8)
        Vt[((size_t)bh * VHD_ + d0 + r) * S_ + s0 + tx] = __float2bfloat16(t[tx][r]);
}

// ---------------------------------------------------------------------------
// MFMA flash attention. Block = (b,h,64 q-rows), 4 waves x 16 q-rows.
// ---------------------------------------------------------------------------
__global__ __launch_bounds__(256) void attn_mfma(
    const bf16* __restrict__ Qp, const bf16* __restrict__ Kh,
    const bf16* __restrict__ Vt, bf16* __restrict__ outp)
{
    __shared__ short Ks[64][200];
    __shared__ short Vs[128][72];
    __shared__ short Ps[4][16][72];

    const int tid = threadIdx.x;
    const int wid = tid >> 6, lane = tid & 63;
    const int l16 = lane & 15;
    const int lk  = (lane >> 4) << 3;
    const int pr  = (lane >> 4) << 2;
    const int q0 = blockIdx.x * 64;
    const int h = blockIdx.y, b = blockIdx.z;
    const int qw = q0 + wid * 16;

    short8_t qf[6];
    const bf16* qbase = Qp + (((size_t)b * S_ + qw + l16) * NH_ + h) * QHD_;
    #pragma unroll
    for (int kk = 0; kk < 6; ++kk)
        qf[kk] = *(const short8_t*)(qbase + kk * 32 + lk);

    const bf16* Khb = Kh + (size_t)(b * NH_ + h) * S_ * QHD_;
    const bf16* Vtb = Vt + (size_t)(b * NH_ + h) * VHD_ * S_;

    f32x4 o[8] = {};
    float mr[4] = {-3.0e38f, -3.0e38f, -3.0e38f, -3.0e38f};
    float lr[4] = {0.f, 0.f, 0.f, 0.f};
    const float scale = 0.07216878364870323f;

    const int krow = tid >> 2, kpart = tid & 3;
    const int vrow = tid >> 1, vpart = tid & 1;

    for (int k0 = 0; k0 <= q0; k0 += 64) {
        {
            const short* src = (const short*)(Khb + (size_t)(k0 + krow) * QHD_) + kpart * 48;
            short8_t t0 = *(const short8_t*)(src);
            short8_t t1 = *(const short8_t*)(src + 8);
            short8_t t2 = *(const short8_t*)(src + 16);
            short8_t t3 = *(const short8_t*)(src + 24);
            short8_t t4 = *(const short8_t*)(src + 32);
            short8_t t5 = *(const short8_t*)(src + 40);
            short* d = &Ks[krow][kpart * 48];
            *(short8_t*)(d) = t0; *(short8_t*)(d + 8) = t1; *(short8_t*)(d + 16) = t2;
            *(short8_t*)(d + 24) = t3; *(short8_t*)(d + 32) = t4; *(short8_t*)(d + 40) = t5;
        }
        {
            const short* src = (const short*)(Vtb + (size_t)vrow * S_ + k0) + vpart * 32;
            short8_t t0 = *(const short8_t*)(src);
            short8_t t1 = *(const short8_t*)(src + 8);
            short8_t t2 = *(const short8_t*)(src + 16);
            short8_t t3 = *(const short8_t*)(src + 24);
            short* d = &Vs[vrow][vpart * 32];
            *(short8_t*)(d) = t0; *(short8_t*)(d + 8) = t1;
            *(short8_t*)(d + 16) = t2; *(short8_t*)(d + 24) = t3;
        }
        __syncthreads();

        f32x4 s[4] = {};
        #pragma unroll
        for (int kk = 0; kk < 6; ++kk) {
            #pragma unroll
            for (int n = 0; n < 4; ++n) {
                short8_t kf = *(const short8_t*)&Ks[n * 16 + l16][kk * 32 + lk];
                s[n] = __builtin_amdgcn_mfma_f32_16x16x32_bf16(qf[kk], kf, s[n], 0, 0, 0);
            }
        }
        #pragma unroll
        for (int n = 0; n < 4; ++n) {
            const int kg = k0 + n * 16 + l16;
            #pragma unroll
            for (int r = 0; r < 4; ++r) {
                if (kg > qw + pr + r) s[n][r] = -3.0e38f;
            }
        }
        float pexp[4][4];
        #pragma unroll
        for (int r = 0; r < 4; ++r) {
            float rm = fmaxf(fmaxf(s[0][r], s[1][r]), fmaxf(s[2][r], s[3][r]));
            rm = fmaxf(rm, __shfl_xor(rm, 1));
            rm = fmaxf(rm, __shfl_xor(rm, 2));
            rm = fmaxf(rm, __shfl_xor(rm, 4));
            rm = fmaxf(rm, __shfl_xor(rm, 8));
            const float mnew = fmaxf(mr[r], rm);
            const float corr = __expf((mr[r] - mnew) * scale);
            mr[r] = mnew;
            float rs = 0.f;
            #pragma unroll
            for (int n = 0; n < 4; ++n) {
                const float p = __expf((s[n][r] - mnew) * scale);
                pexp[n][r] = p;
                rs += p;
            }
            rs += __shfl_xor(rs, 1);
            rs += __shfl_xor(rs, 2);
            rs += __shfl_xor(rs, 4);
            rs += __shfl_xor(rs, 8);
            lr[r] = lr[r] * corr + rs;
            #pragma unroll
            for (int n = 0; n < 8; ++n) o[n][r] *= corr;
        }
        #pragma unroll
        for (int n = 0; n < 4; ++n) {
            #pragma unroll
            for (int r = 0; r < 4; ++r) {
                union { bf16 hh; short u; } cv;
                cv.hh = __float2bfloat16(pexp[n][r]);
                Ps[wid][pr + r][n * 16 + l16] = cv.u;
            }
        }
        #pragma unroll
        for (int kk2 = 0; kk2 < 2; ++kk2) {
            short8_t pf = *(const short8_t*)&Ps[wid][l16][kk2 * 32 + lk];
            #pragma unroll
            for (int n = 0; n < 8; ++n) {
                short8_t vf = *(const short8_t*)&Vs[n * 16 + l16][kk2 * 32 + lk];
                o[n] = __builtin_amdgcn_mfma_f32_16x16x32_bf16(pf, vf, o[n], 0, 0, 0);
            }
        }
        __syncthreads();
    }

    float inv[4];
    #pragma unroll
    for (int r = 0; r < 4; ++r) inv[r] = 1.f / lr[r];
    bf16* ob = outp + (((size_t)b * S_ + qw + pr) * NH_ + h) * VHD_;
    #pragma unroll
    for (int r = 0; r < 4; ++r)
        #pragma unroll
        for (int n = 0; n < 8; ++n)
            ob[(size_t)r * (NH_ * VHD_) + n * 16 + l16] = __float2bfloat16(o[n][r] * inv[r]);
}

// ---------------------------------------------------------------------------
// Launch
// ---------------------------------------------------------------------------
extern "C" void kernel_launch(void* const* d_in, const int* in_sizes, int n_in,
                              void* d_out, int out_size, void* d_ws, size_t ws_size,
                              hipStream_t stream)
{
    const float* hidden  = (const float*)d_in[0];
    const float* ln1_w   = (const float*)d_in[1];
    const float* q_a_k   = (const float*)d_in[2];
    const float* q_a_ln  = (const float*)d_in[3];
    const float* q_b_k   = (const float*)d_in[4];
    const float* kv_a_k  = (const float*)d_in[5];
    const float* kv_a_ln = (const float*)d_in[6];
    const float* kv_b_k  = (const float*)d_in[7];
    const float* o_k     = (const float*)d_in[8];
    const float* ln2_w   = (const float*)d_in[9];
    const float* gate_k  = (const float*)d_in[10];
    const float* up_k    = (const float*)d_in[11];
    const float* down_k  = (const float*)d_in[12];
    const float* sinT    = (const float*)d_in[13];
    const float* cosT    = (const float*)d_in[14];
    const int*   pos     = (const int*)d_in[15];
    float* out = (float*)d_out;
    char* ws = (char*)d_ws;

    // ---- Phase-1 workspace layout ----
    bf16* qaT   = (bf16*)(ws + 0);            // [1536][2048]  6,291,456
    bf16* qbT   = (bf16*)(ws + 6291456);      // [3072][1536]  9,437,184
    bf16* kvaT  = (bf16*)(ws + 15728640);     // [640][2048]   2,621,440
    bf16* kvbT  = (bf16*)(ws + 18350080);     // [4096][512]   4,194,304
    bf16* oT    = (bf16*)(ws + 22544384);     // [2048][2048]  8,388,608
    bf16* Xb    = (bf16*)(ws + 30932992);     // [4096][2048] 16,777,216
    bf16* QAb   = (bf16*)(ws + 47710208);     // [4096][1536] 12,582,912
    bf16* CKVNb = (bf16*)(ws + 60293120);     // [4096][512]   4,194,304
    bf16* Qb    = (bf16*)(ws + 64487424);     // [4096][3072] 25,165,824
    float* CKV  = (float*)(ws + 89653248);    // [4096][640]  10,485,760
    float* KV   = (float*)(ws + 100139008);   // [4096][4096] 67,108,864
    bf16* ATTNb = (bf16*)(ws + 167247872);    // [4096][2048] 16,777,216
    bf16* Vt    = (bf16*)(ws + 0);            // overlays dead qaT/qbT/kvaT
    bf16* Kh    = (bf16*)(ws + 30932992);     // overlays dead Xb+QAb
    // ---- Phase-2 layout ----
    bf16* gateT = (bf16*)(ws + 0);            // [8192][2048] 33,554,432
    bf16* upT   = (bf16*)(ws + 33554432);     // [8192][2048] 33,554,432
    bf16* downT = (bf16*)(ws + 67108864);     // [2048][8192] 33,554,432
    bf16* X2b   = (bf16*)(ws + 100663296);    // [4096][2048] 16,777,216
    bf16* MLPb  = (bf16*)(ws + 117440512);    // [4096][8192] 67,108,864

    const dim3 tb(32, 8);

    // 0. weight transposes (attention-phase weights)
    transp_bf16<<<dim3(1536 / 32, 2048 / 32), tb, 0, stream>>>(q_a_k, qaT, 2048, 1536, 1536);
    transp_bf16<<<dim3(3072 / 32, 1536 / 32), tb, 0, stream>>>(q_b_k, qbT, 1536, 3072, 3072);
    transp_bf16<<<dim3(640 / 32, 2048 / 32), tb, 0, stream>>>(kv_a_k, kvaT, 2048, 576, 640);
    transp_bf16<<<dim3(4096 / 32, 512 / 32), tb, 0, stream>>>(kv_b_k, kvbT, 512, 4096, 4096);
    transp_bf16<<<dim3(2048 / 32, 2048 / 32), tb, 0, stream>>>(o_k, oT, 2048, 2048, 2048);

    // 1. Xb = rmsnorm(hidden)
    rmsnorm2<float, bf16><<<BS_, 256, 0, stream>>>(hidden, ln1_w, Xb, H_, H_, H_);
    // 2. QAb = Xb @ qaT   (N=1536: 128-tile kernel, grid 12x32)
    gemm_bf16<0, bf16><<<dim3(QL_ / 128, BS_ / 128), 256, 0, stream>>>(
        Xb, qaT, nullptr, nullptr, QAb, BS_, QL_, H_);
    // 3. QAb = rmsnorm(QAb) in place
    rmsnorm2<bf16, bf16><<<BS_, 256, 0, stream>>>(QAb, q_a_ln, QAb, QL_, QL_, QL_);
    // 4. Qb = QAb @ qbT   (256-tile, grid 12x16)
    gemm256<0, bf16><<<dim3((NH_ * QHD_) / 256, BS_ / 256), 512, 0, stream>>>(
        QAb, qbT, nullptr, nullptr, Qb, BS_, NH_ * QHD_, QL_);
    // 5. CKV = Xb @ kvaT (fp32, padded width 640; 128-tile)
    gemm_bf16<0, float><<<dim3(CKVP_ / 128, BS_ / 128), 256, 0, stream>>>(
        Xb, kvaT, nullptr, nullptr, CKV, BS_, CKVP_, H_);
    // 6. CKVNb = rmsnorm(CKV[:, :512])
    rmsnorm2<float, bf16><<<BS_, 256, 0, stream>>>(CKV, kv_a_ln, CKVNb, KVL_, CKVP_, KVL_);
    // 7. KV = CKVNb @ kvbT (fp32, 256-tile, grid 16x16)
    gemm256<0, float><<<dim3((NH_ * KVW_) / 256, BS_ / 256), 512, 0, stream>>>(
        CKVNb, kvbT, nullptr, nullptr, KV, BS_, NH_ * KVW_, KVL_);
    // 8. RoPE in place on Qb and CKV k_pe
    rope_kernel<<<(BS_ * NH_ + BS_) / 4, 256, 0, stream>>>(Qb, CKV, pos, sinT, cosT);
    // 9. pack K and V^T into head-major bf16
    pack_k<<<2048, 256, 0, stream>>>(KV, CKV, Kh);
    pack_vt<<<dim3(S_ / 32, VHD_ / 32, B_ * NH_), 256, 0, stream>>>(KV, Vt);
    // 10. MFMA flash attention -> ATTNb
    attn_mfma<<<dim3(S_ / 64, NH_, B_), 256, 0, stream>>>(Qb, Kh, Vt, ATTNb);
    // 11. d_out = ATTNb @ oT + hidden (fp32, 256-tile, grid 8x16)
    gemm256<1, float><<<dim3(H_ / 256, BS_ / 256), 512, 0, stream>>>(
        ATTNb, oT, hidden, nullptr, out, BS_, H_, NH_ * VHD_);

    // 12. MLP-phase weight transposes
    transp_bf16<<<dim3(8192 / 32, 2048 / 32), tb, 0, stream>>>(gate_k, gateT, 2048, 8192, 8192);
    transp_bf16<<<dim3(8192 / 32, 2048 / 32), tb, 0, stream>>>(up_k, upT, 2048, 8192, 8192);
    transp_bf16<<<dim3(2048 / 32, 8192 / 32), tb, 0, stream>>>(down_k, downT, 8192, 2048, 2048);

    // 13. X2b = rmsnorm(d_out)
    rmsnorm2<float, bf16><<<BS_, 256, 0, stream>>>(out, ln2_w, X2b, H_, H_, H_);
    // 14. MLPb = X2b @ gateT (256-tile, grid 32x16)
    gemm256<0, bf16><<<dim3(FF_ / 256, BS_ / 256), 512, 0, stream>>>(
        X2b, gateT, nullptr, nullptr, MLPb, BS_, FF_, H_);
    // 15. MLPb = silu(MLPb) * (X2b @ upT) (256-tile)
    gemm256<2, bf16><<<dim3(FF_ / 256, BS_ / 256), 512, 0, stream>>>(
        X2b, upT, nullptr, MLPb, MLPb, BS_, FF_, H_);
    // 16. d_out = MLPb @ downT + d_out (256-tile, grid 8x16)
    gemm256<1, float><<<dim3(H_ / 256, BS_ / 256), 512, 0, stream>>>(
        MLPb, downT, out, nullptr, out, BS_, H_, FF_);
}